// Round 1
// baseline (856.316 us; speedup 1.0000x reference)
//
#include <hip/hip_runtime.h>

#define N_NODES 20000
#define N_EDGES 320000
#define N_FEAT 128
#define MLP_HID 64
#define N_GRAPHS 16
#define N_LAYERS 5
#define EPS 1e-5f

// ---------------- CSR build ----------------

__global__ __launch_bounds__(256) void k_deg(const int* __restrict__ dst, int* __restrict__ deg) {
  int e = blockIdx.x * 256 + threadIdx.x;  // grid exact: 1250*256 = 320000
  atomicAdd(&deg[dst[e]], 1);
}

__global__ __launch_bounds__(256) void k_cnt(const int* __restrict__ batch, int* __restrict__ cnti) {
  int n = blockIdx.x * 256 + threadIdx.x;
  if (n < N_NODES) atomicAdd(&cnti[batch[n]], 1);
}

__global__ __launch_bounds__(1024) void k_scan(const int* __restrict__ deg, int* __restrict__ rowptr,
                                               int* __restrict__ cursor, const int* __restrict__ cnti,
                                               float* __restrict__ cntf) {
  __shared__ int sdata[1024];
  constexpr int CH = 20;  // 1024*20 = 20480 >= 20000
  int t = threadIdx.x;
  int base = t * CH;
  int loc[CH];
  int partial = 0;
#pragma unroll
  for (int i = 0; i < CH; i++) {
    int idx = base + i;
    int v = (idx < N_NODES) ? deg[idx] : 0;
    loc[i] = v;
    partial += v;
  }
  sdata[t] = partial;
  __syncthreads();
  for (int off = 1; off < 1024; off <<= 1) {
    int v = (t >= off) ? sdata[t - off] : 0;
    __syncthreads();
    sdata[t] += v;
    __syncthreads();
  }
  int run = sdata[t] - partial;  // exclusive prefix
#pragma unroll
  for (int i = 0; i < CH; i++) {
    int idx = base + i;
    if (idx < N_NODES) {
      rowptr[idx] = run;
      cursor[idx] = run;
      run += loc[i];
    }
  }
  if (t == 1023) rowptr[N_NODES] = sdata[1023];
  if (t < N_GRAPHS) cntf[t] = fmaxf((float)cnti[t], 1.0f);
}

__global__ __launch_bounds__(256) void k_fill(const int* __restrict__ src, const int* __restrict__ dst,
                                              int* __restrict__ cursor, int* __restrict__ src_sorted) {
  int e = blockIdx.x * 256 + threadIdx.x;  // grid exact
  int d = dst[e];
  int p = atomicAdd(&cursor[d], 1);
  src_sorted[p] = src[e];
}

// ---------------- per-node MLP: m = relu(h@W1+b1)@W2+b2 ----------------

__global__ __launch_bounds__(256) void k_mlp(const float* __restrict__ hin, float* __restrict__ mout,
                                             const float* __restrict__ W1, const float* __restrict__ b1,
                                             const float* __restrict__ W2, const float* __restrict__ b2) {
  __shared__ float W1s[128 * 64];
  __shared__ float W2s[64 * 128];
  __shared__ float hs[16][128];
  __shared__ float hidS[16][64];
  __shared__ float b1s[64];
  __shared__ float b2s[128];
  int t = threadIdx.x;
  int r0 = blockIdx.x * 16;  // grid exact: 1250*16 = 20000
  {
    float4* w1v = (float4*)W1s;
    const float4* w1g = (const float4*)W1;
    float4* w2v = (float4*)W2s;
    const float4* w2g = (const float4*)W2;
    for (int i = t; i < 2048; i += 256) {
      w1v[i] = w1g[i];
      w2v[i] = w2g[i];
    }
    float4* hv = (float4*)hs;
    const float4* hg = (const float4*)(hin + (size_t)r0 * 128);
    for (int i = t; i < 512; i += 256) hv[i] = hg[i];
    if (t < 64) b1s[t] = b1[t];
    if (t < 128) b2s[t] = b2[t];
  }
  __syncthreads();
  // phase 1: hid[16][64]
  {
    int j = t & 63, rr = t >> 6;  // rows rr, rr+4, rr+8, rr+12
    float a0 = 0.f, a1 = 0.f, a2 = 0.f, a3 = 0.f;
#pragma unroll
    for (int c = 0; c < 128; c += 4) {
      float w0 = W1s[(c + 0) * 64 + j];
      float w1 = W1s[(c + 1) * 64 + j];
      float w2 = W1s[(c + 2) * 64 + j];
      float w3 = W1s[(c + 3) * 64 + j];
      float4 h0 = *(const float4*)&hs[rr][c];
      float4 h1 = *(const float4*)&hs[rr + 4][c];
      float4 h2 = *(const float4*)&hs[rr + 8][c];
      float4 h3 = *(const float4*)&hs[rr + 12][c];
      a0 += h0.x * w0 + h0.y * w1 + h0.z * w2 + h0.w * w3;
      a1 += h1.x * w0 + h1.y * w1 + h1.z * w2 + h1.w * w3;
      a2 += h2.x * w0 + h2.y * w1 + h2.z * w2 + h2.w * w3;
      a3 += h3.x * w0 + h3.y * w1 + h3.z * w2 + h3.w * w3;
    }
    float bb = b1s[j];
    hidS[rr][j] = fmaxf(a0 + bb, 0.0f);
    hidS[rr + 4][j] = fmaxf(a1 + bb, 0.0f);
    hidS[rr + 8][j] = fmaxf(a2 + bb, 0.0f);
    hidS[rr + 12][j] = fmaxf(a3 + bb, 0.0f);
  }
  __syncthreads();
  // phase 2: m[16][128]
  {
    int j = t & 127, r2 = t >> 7;  // rows r2 + 2q
    float acc[8];
#pragma unroll
    for (int q = 0; q < 8; q++) acc[q] = 0.0f;
#pragma unroll
    for (int k = 0; k < 64; k += 4) {
      float w0 = W2s[(k + 0) * 128 + j];
      float w1 = W2s[(k + 1) * 128 + j];
      float w2 = W2s[(k + 2) * 128 + j];
      float w3 = W2s[(k + 3) * 128 + j];
#pragma unroll
      for (int q = 0; q < 8; q++) {
        float4 hh = *(const float4*)&hidS[r2 + 2 * q][k];
        acc[q] += hh.x * w0 + hh.y * w1 + hh.z * w2 + hh.w * w3;
      }
    }
    float bb = b2s[j];
#pragma unroll
    for (int q = 0; q < 8; q++) mout[(size_t)(r0 + r2 + 2 * q) * 128 + j] = acc[q] + bb;
  }
}

// ---------------- scatter-add: g[n] = m[n] + sum_{e: dst=n} m[src[e]] ----------------

__global__ __launch_bounds__(256) void k_scatter(const float* __restrict__ m, float* __restrict__ g,
                                                 const int* __restrict__ rowptr, const int* __restrict__ srcs) {
  int wid = (blockIdx.x * 256 + threadIdx.x) >> 6;  // node, grid exact 5000*4 waves = 20000
  int lane = threadIdx.x & 63;
  const float2* m2 = (const float2*)m;
  float2 acc = m2[(size_t)wid * 64 + lane];  // self loop
  float2 s1 = {0.f, 0.f}, s2 = {0.f, 0.f}, s3 = {0.f, 0.f};
  int e0 = rowptr[wid], e1 = rowptr[wid + 1];
  int e = e0;
  for (; e + 4 <= e1; e += 4) {
    int i0 = srcs[e], i1 = srcs[e + 1], i2 = srcs[e + 2], i3 = srcs[e + 3];
    float2 v0 = m2[(size_t)i0 * 64 + lane];
    float2 v1 = m2[(size_t)i1 * 64 + lane];
    float2 v2 = m2[(size_t)i2 * 64 + lane];
    float2 v3 = m2[(size_t)i3 * 64 + lane];
    acc.x += v0.x; acc.y += v0.y;
    s1.x += v1.x; s1.y += v1.y;
    s2.x += v2.x; s2.y += v2.y;
    s3.x += v3.x; s3.y += v3.y;
  }
  for (; e < e1; e++) {
    int i0 = srcs[e];
    float2 v0 = m2[(size_t)i0 * 64 + lane];
    acc.x += v0.x; acc.y += v0.y;
  }
  acc.x += s1.x + s2.x + s3.x;
  acc.y += s1.y + s2.y + s3.y;
  ((float2*)g)[(size_t)wid * 64 + lane] = acc;
}

// ---------------- segment sums over sorted batch ----------------

__global__ __launch_bounds__(128) void k_segsum(const float* __restrict__ in, const int* __restrict__ batch,
                                                float* __restrict__ outbuf) {
  int n0 = blockIdx.x * 64;
  int c = threadIdx.x;
  int nend = min(n0 + 64, N_NODES);
  int curg = batch[n0];
  float acc = 0.0f;
  for (int n = n0; n < nend; n++) {
    int gg = batch[n];
    if (gg != curg) {
      atomicAdd(&outbuf[curg * 128 + c], acc);
      acc = 0.0f;
      curg = gg;
    }
    acc += in[(size_t)n * 128 + c];
  }
  atomicAdd(&outbuf[curg * 128 + c], acc);
}

__global__ __launch_bounds__(128) void k_varsum(const float* __restrict__ in, const int* __restrict__ batch,
                                                const float* __restrict__ meansum, float* __restrict__ varsum,
                                                const float* __restrict__ cntf, const float* __restrict__ a) {
  int n0 = blockIdx.x * 64;
  int c = threadIdx.x;
  int nend = min(n0 + 64, N_NODES);
  float a_c = a[c];
  int curg = batch[n0];
  float mv = meansum[curg * 128 + c] / cntf[curg];
  float acc = 0.0f;
  for (int n = n0; n < nend; n++) {
    int gg = batch[n];
    if (gg != curg) {
      atomicAdd(&varsum[curg * 128 + c], acc);
      acc = 0.0f;
      curg = gg;
      mv = meansum[curg * 128 + c] / cntf[curg];
    }
    float d = in[(size_t)n * 128 + c] - a_c * mv;
    acc += d * d;
  }
  atomicAdd(&varsum[curg * 128 + c], acc);
}

// ---------------- normalize + affine + relu + residual ----------------

__global__ __launch_bounds__(256) void k_apply(const float* __restrict__ gin, float* __restrict__ h,
                                               const int* __restrict__ batch,
                                               const float* __restrict__ meansum, const float* __restrict__ varsum,
                                               const float* __restrict__ cntf,
                                               const float* __restrict__ w, const float* __restrict__ b,
                                               const float* __restrict__ a, int residual) {
  int idx = blockIdx.x * 256 + threadIdx.x;  // grid exact: 10000*256 = 2,560,000
  int n = idx >> 7, c = idx & 127;
  int gg = batch[n];
  float invc = 1.0f / cntf[gg];
  float mean = meansum[gg * 128 + c] * invc;
  float var = varsum[gg * 128 + c] * invc;
  float d = gin[idx] - a[c] * mean;
  float y = w[c] * (d * rsqrtf(var + EPS)) + b[c];
  y = fmaxf(y, 0.0f);
  h[idx] = residual ? (y + h[idx]) : y;
}

// ---------------- final pooled @ lin_w + lin_b ----------------

__global__ __launch_bounds__(256) void k_final(const float* __restrict__ pooled, const float* __restrict__ cntf,
                                               const float* __restrict__ lw, const float* __restrict__ lb,
                                               float* __restrict__ out) {
  int lane = threadIdx.x & 63, wave = threadIdx.x >> 6;
  for (int gi = 0; gi < 4; gi++) {
    int gidx = wave * 4 + gi;
    float s = pooled[gidx * 128 + lane] * lw[lane] + pooled[gidx * 128 + 64 + lane] * lw[64 + lane];
    for (int o = 32; o >= 1; o >>= 1) s += __shfl_down(s, o);
    if (lane == 0) out[gidx] = s / cntf[gidx] + lb[0];
  }
}

// ---------------- host ----------------

extern "C" void kernel_launch(void* const* d_in, const int* in_sizes, int n_in,
                              void* d_out, int out_size, void* d_ws, size_t ws_size,
                              hipStream_t stream) {
  const float* x = (const float*)d_in[0];
  const int* ei = (const int*)d_in[1];
  const int* batch = (const int*)d_in[2];
  const float* W1 = (const float*)d_in[3];
  const float* b1 = (const float*)d_in[4];
  const float* W2 = (const float*)d_in[5];
  const float* b2 = (const float*)d_in[6];
  const float* gnw = (const float*)d_in[7];
  const float* gnb = (const float*)d_in[8];
  const float* gna = (const float*)d_in[9];
  const float* lw = (const float*)d_in[10];
  const float* lb = (const float*)d_in[11];
  float* out = (float*)d_out;

  const int* srcI = ei;
  const int* dstI = ei + N_EDGES;

  char* p = (char*)d_ws;
  float* hbuf = (float*)(p + 0);                 // 10,240,000 B
  float* mbuf = (float*)(p + 10240000);          // 10,240,000 B
  float* gbuf = (float*)(p + 20480000);          // 10,240,000 B
  int* src_sorted = (int*)(p + 30720000);        // 1,280,000 B
  int* rowptr = (int*)(p + 32000000);            // 80,004 -> 80,128 B
  int* cursor = (int*)(p + 32080128);            // 80,000 -> 80,128 B
  int* deg = (int*)(p + 32160256);               // 80,000 -> 80,128 B
  int* cnti = (int*)(p + 32240384);              // 64 -> 128 B
  float* cntf = (float*)(p + 32240512);          // 64 -> 128 B
  float* meansum = (float*)(p + 32240640);       // 8192 B
  float* varsum = (float*)(p + 32248832);        // 8192 B
  float* pooled = (float*)(p + 32257024);        // 8192 B

  // CSR build (once per call; edges are layer-invariant)
  hipMemsetAsync(deg, 0, N_NODES * sizeof(int), stream);
  hipMemsetAsync(cnti, 0, N_GRAPHS * sizeof(int), stream);
  k_deg<<<N_EDGES / 256, 256, 0, stream>>>(dstI, deg);
  k_cnt<<<(N_NODES + 255) / 256, 256, 0, stream>>>(batch, cnti);
  k_scan<<<1, 1024, 0, stream>>>(deg, rowptr, cursor, cnti, cntf);
  k_fill<<<N_EDGES / 256, 256, 0, stream>>>(srcI, dstI, cursor, src_sorted);

  const float* hin = x;
  for (int i = 0; i < N_LAYERS; i++) {
    k_mlp<<<N_NODES / 16, 256, 0, stream>>>(hin, mbuf, W1 + (size_t)i * 128 * 64, b1 + (size_t)i * 64,
                                            W2 + (size_t)i * 64 * 128, b2 + (size_t)i * 128);
    k_scatter<<<N_NODES / 4, 256, 0, stream>>>(mbuf, gbuf, rowptr, src_sorted);
    hipMemsetAsync(meansum, 0, N_GRAPHS * N_FEAT * sizeof(float), stream);
    k_segsum<<<(N_NODES + 63) / 64, 128, 0, stream>>>(gbuf, batch, meansum);
    hipMemsetAsync(varsum, 0, N_GRAPHS * N_FEAT * sizeof(float), stream);
    k_varsum<<<(N_NODES + 63) / 64, 128, 0, stream>>>(gbuf, batch, meansum, varsum, cntf, gna + (size_t)i * 128);
    k_apply<<<N_NODES * N_FEAT / 256, 256, 0, stream>>>(gbuf, hbuf, batch, meansum, varsum, cntf,
                                                        gnw + (size_t)i * 128, gnb + (size_t)i * 128,
                                                        gna + (size_t)i * 128, i > 0 ? 1 : 0);
    hin = hbuf;
  }

  hipMemsetAsync(pooled, 0, N_GRAPHS * N_FEAT * sizeof(float), stream);
  k_segsum<<<(N_NODES + 63) / 64, 128, 0, stream>>>(hbuf, batch, pooled);
  k_final<<<1, 256, 0, stream>>>(pooled, cntf, lw, lb, out);
}

// Round 2
// 515.899 us; speedup vs baseline: 1.6599x; 1.6599x over previous
//
#include <hip/hip_runtime.h>

#define N_NODES 20000
#define N_EDGES 320000
#define N_FEAT 128
#define MLP_HID 64
#define N_GRAPHS 16
#define N_LAYERS 5
#define EPS 1e-5f

// ---------------- CSR build ----------------

__global__ __launch_bounds__(256) void k_deg(const int* __restrict__ dst, int* __restrict__ deg) {
  int e = blockIdx.x * 256 + threadIdx.x;  // grid exact: 1250*256 = 320000
  atomicAdd(&deg[dst[e]], 1);
}

__global__ __launch_bounds__(1024) void k_scan(const int* __restrict__ deg, int* __restrict__ rowptr,
                                               int* __restrict__ cursor, const int* __restrict__ batch,
                                               float* __restrict__ cntf) {
  __shared__ int sdata[1024];
  __shared__ int spos[17];
  constexpr int CH = 20;  // 1024*20 = 20480 >= 20000
  int t = threadIdx.x;
  int base = t * CH;
  int loc[CH];
  int partial = 0;
#pragma unroll
  for (int i = 0; i < CH; i++) {
    int idx = base + i;
    int v = (idx < N_NODES) ? deg[idx] : 0;
    loc[i] = v;
    partial += v;
  }
  sdata[t] = partial;
  __syncthreads();
  for (int off = 1; off < 1024; off <<= 1) {
    int v = (t >= off) ? sdata[t - off] : 0;
    __syncthreads();
    sdata[t] += v;
    __syncthreads();
  }
  int run = sdata[t] - partial;  // exclusive prefix
#pragma unroll
  for (int i = 0; i < CH; i++) {
    int idx = base + i;
    if (idx < N_NODES) {
      rowptr[idx] = run;
      cursor[idx] = run;
      run += loc[i];
    }
  }
  if (t == 1023) rowptr[N_NODES] = sdata[1023];
  // per-graph counts via binary search on sorted batch (replaces the
  // catastrophically-contended k_cnt atomic histogram: 227us -> ~0)
  if (t < 17) {
    int lo = 0, hi = N_NODES;
    while (lo < hi) {
      int mid = (lo + hi) >> 1;
      if (batch[mid] < t) lo = mid + 1; else hi = mid;
    }
    spos[t] = lo;
  }
  __syncthreads();
  if (t < N_GRAPHS) cntf[t] = fmaxf((float)(spos[t + 1] - spos[t]), 1.0f);
}

__global__ __launch_bounds__(256) void k_fill(const int* __restrict__ src, const int* __restrict__ dst,
                                              int* __restrict__ cursor, int* __restrict__ src_sorted) {
  int e = blockIdx.x * 256 + threadIdx.x;  // grid exact
  int d = dst[e];
  int p = atomicAdd(&cursor[d], 1);
  src_sorted[p] = src[e];
}

// ---------------- per-node MLP: m = relu(h@W1+b1)@W2+b2 ----------------

__global__ __launch_bounds__(256) void k_mlp(const float* __restrict__ hin, float* __restrict__ mout,
                                             const float* __restrict__ W1, const float* __restrict__ b1,
                                             const float* __restrict__ W2, const float* __restrict__ b2) {
  __shared__ float W1s[128 * 64];
  __shared__ float W2s[64 * 128];
  __shared__ float hs[16][128];
  __shared__ float hidS[16][64];
  __shared__ float b1s[64];
  __shared__ float b2s[128];
  int t = threadIdx.x;
  int r0 = blockIdx.x * 16;  // grid exact: 1250*16 = 20000
  {
    float4* w1v = (float4*)W1s;
    const float4* w1g = (const float4*)W1;
    float4* w2v = (float4*)W2s;
    const float4* w2g = (const float4*)W2;
    for (int i = t; i < 2048; i += 256) {
      w1v[i] = w1g[i];
      w2v[i] = w2g[i];
    }
    float4* hv = (float4*)hs;
    const float4* hg = (const float4*)(hin + (size_t)r0 * 128);
    for (int i = t; i < 512; i += 256) hv[i] = hg[i];
    if (t < 64) b1s[t] = b1[t];
    if (t < 128) b2s[t] = b2[t];
  }
  __syncthreads();
  // phase 1: hid[16][64]
  {
    int j = t & 63, rr = t >> 6;  // rows rr, rr+4, rr+8, rr+12
    float a0 = 0.f, a1 = 0.f, a2 = 0.f, a3 = 0.f;
#pragma unroll
    for (int c = 0; c < 128; c += 4) {
      float w0 = W1s[(c + 0) * 64 + j];
      float w1 = W1s[(c + 1) * 64 + j];
      float w2 = W1s[(c + 2) * 64 + j];
      float w3 = W1s[(c + 3) * 64 + j];
      float4 h0 = *(const float4*)&hs[rr][c];
      float4 h1 = *(const float4*)&hs[rr + 4][c];
      float4 h2 = *(const float4*)&hs[rr + 8][c];
      float4 h3 = *(const float4*)&hs[rr + 12][c];
      a0 += h0.x * w0 + h0.y * w1 + h0.z * w2 + h0.w * w3;
      a1 += h1.x * w0 + h1.y * w1 + h1.z * w2 + h1.w * w3;
      a2 += h2.x * w0 + h2.y * w1 + h2.z * w2 + h2.w * w3;
      a3 += h3.x * w0 + h3.y * w1 + h3.z * w2 + h3.w * w3;
    }
    float bb = b1s[j];
    hidS[rr][j] = fmaxf(a0 + bb, 0.0f);
    hidS[rr + 4][j] = fmaxf(a1 + bb, 0.0f);
    hidS[rr + 8][j] = fmaxf(a2 + bb, 0.0f);
    hidS[rr + 12][j] = fmaxf(a3 + bb, 0.0f);
  }
  __syncthreads();
  // phase 2: m[16][128]
  {
    int j = t & 127, r2 = t >> 7;  // rows r2 + 2q
    float acc[8];
#pragma unroll
    for (int q = 0; q < 8; q++) acc[q] = 0.0f;
#pragma unroll
    for (int k = 0; k < 64; k += 4) {
      float w0 = W2s[(k + 0) * 128 + j];
      float w1 = W2s[(k + 1) * 128 + j];
      float w2 = W2s[(k + 2) * 128 + j];
      float w3 = W2s[(k + 3) * 128 + j];
#pragma unroll
      for (int q = 0; q < 8; q++) {
        float4 hh = *(const float4*)&hidS[r2 + 2 * q][k];
        acc[q] += hh.x * w0 + hh.y * w1 + hh.z * w2 + hh.w * w3;
      }
    }
    float bb = b2s[j];
#pragma unroll
    for (int q = 0; q < 8; q++) mout[(size_t)(r0 + r2 + 2 * q) * 128 + j] = acc[q] + bb;
  }
}

// ---------------- scatter-add: g[n] = m[n] + sum_{e: dst=n} m[src[e]] ----------------

__global__ __launch_bounds__(256) void k_scatter(const float* __restrict__ m, float* __restrict__ g,
                                                 const int* __restrict__ rowptr, const int* __restrict__ srcs) {
  int wid = (blockIdx.x * 256 + threadIdx.x) >> 6;  // node, grid exact 5000*4 waves = 20000
  int lane = threadIdx.x & 63;
  const float2* m2 = (const float2*)m;
  float2 acc = m2[(size_t)wid * 64 + lane];  // self loop
  float2 s1 = {0.f, 0.f}, s2 = {0.f, 0.f}, s3 = {0.f, 0.f};
  int e0 = rowptr[wid], e1 = rowptr[wid + 1];
  int e = e0;
  for (; e + 4 <= e1; e += 4) {
    int i0 = srcs[e], i1 = srcs[e + 1], i2 = srcs[e + 2], i3 = srcs[e + 3];
    float2 v0 = m2[(size_t)i0 * 64 + lane];
    float2 v1 = m2[(size_t)i1 * 64 + lane];
    float2 v2 = m2[(size_t)i2 * 64 + lane];
    float2 v3 = m2[(size_t)i3 * 64 + lane];
    acc.x += v0.x; acc.y += v0.y;
    s1.x += v1.x; s1.y += v1.y;
    s2.x += v2.x; s2.y += v2.y;
    s3.x += v3.x; s3.y += v3.y;
  }
  for (; e < e1; e++) {
    int i0 = srcs[e];
    float2 v0 = m2[(size_t)i0 * 64 + lane];
    acc.x += v0.x; acc.y += v0.y;
  }
  acc.x += s1.x + s2.x + s3.x;
  acc.y += s1.y + s2.y + s3.y;
  ((float2*)g)[(size_t)wid * 64 + lane] = acc;
}

// ---------------- one-pass segment stats: s1 = sum(h), s2 = sum(h^2) ----------------

#define STAT_CHUNK 25  // 800 blocks * 25 = 20000 exact

__global__ __launch_bounds__(128) void k_stats(const float* __restrict__ in, const int* __restrict__ batch,
                                               float* __restrict__ s1, float* __restrict__ s2) {
  int n0 = blockIdx.x * STAT_CHUNK;
  int c = threadIdx.x;
  int nend = n0 + STAT_CHUNK;
  int curg = batch[n0];
  float a1 = 0.0f, a2 = 0.0f;
  for (int n = n0; n < nend; n++) {
    int gg = batch[n];
    if (gg != curg) {
      atomicAdd(&s1[curg * 128 + c], a1);
      atomicAdd(&s2[curg * 128 + c], a2);
      a1 = 0.0f; a2 = 0.0f;
      curg = gg;
    }
    float v = in[(size_t)n * 128 + c];
    a1 += v;
    a2 += v * v;
  }
  atomicAdd(&s1[curg * 128 + c], a1);
  atomicAdd(&s2[curg * 128 + c], a2);
}

// sum-only variant for the final pooling
__global__ __launch_bounds__(128) void k_segsum(const float* __restrict__ in, const int* __restrict__ batch,
                                                float* __restrict__ outbuf) {
  int n0 = blockIdx.x * STAT_CHUNK;
  int c = threadIdx.x;
  int nend = n0 + STAT_CHUNK;
  int curg = batch[n0];
  float acc = 0.0f;
  for (int n = n0; n < nend; n++) {
    int gg = batch[n];
    if (gg != curg) {
      atomicAdd(&outbuf[curg * 128 + c], acc);
      acc = 0.0f;
      curg = gg;
    }
    acc += in[(size_t)n * 128 + c];
  }
  atomicAdd(&outbuf[curg * 128 + c], acc);
}

// ---------------- normalize + affine + relu + residual ----------------
// var = E[(h - a*mean)^2] = E[h^2] - mean^2*(2a - a^2)

__global__ __launch_bounds__(256) void k_apply(const float* __restrict__ gin, float* __restrict__ h,
                                               const int* __restrict__ batch,
                                               const float* __restrict__ s1, const float* __restrict__ s2,
                                               const float* __restrict__ cntf,
                                               const float* __restrict__ w, const float* __restrict__ b,
                                               const float* __restrict__ a, int residual) {
  int idx = blockIdx.x * 256 + threadIdx.x;  // grid exact: 10000*256 = 2,560,000
  int n = idx >> 7, c = idx & 127;
  int gg = batch[n];
  float invc = 1.0f / cntf[gg];
  float mean = s1[gg * 128 + c] * invc;
  float ex2 = s2[gg * 128 + c] * invc;
  float ac = a[c];
  float var = fmaxf(ex2 - mean * mean * (2.0f * ac - ac * ac), 0.0f);
  float d = gin[idx] - ac * mean;
  float y = w[c] * (d * rsqrtf(var + EPS)) + b[c];
  y = fmaxf(y, 0.0f);
  h[idx] = residual ? (y + h[idx]) : y;
}

// ---------------- final pooled @ lin_w + lin_b ----------------

__global__ __launch_bounds__(256) void k_final(const float* __restrict__ pooled, const float* __restrict__ cntf,
                                               const float* __restrict__ lw, const float* __restrict__ lb,
                                               float* __restrict__ out) {
  int lane = threadIdx.x & 63, wave = threadIdx.x >> 6;
  for (int gi = 0; gi < 4; gi++) {
    int gidx = wave * 4 + gi;
    float s = pooled[gidx * 128 + lane] * lw[lane] + pooled[gidx * 128 + 64 + lane] * lw[64 + lane];
    for (int o = 32; o >= 1; o >>= 1) s += __shfl_down(s, o);
    if (lane == 0) out[gidx] = s / cntf[gidx] + lb[0];
  }
}

// ---------------- host ----------------

extern "C" void kernel_launch(void* const* d_in, const int* in_sizes, int n_in,
                              void* d_out, int out_size, void* d_ws, size_t ws_size,
                              hipStream_t stream) {
  const float* x = (const float*)d_in[0];
  const int* ei = (const int*)d_in[1];
  const int* batch = (const int*)d_in[2];
  const float* W1 = (const float*)d_in[3];
  const float* b1 = (const float*)d_in[4];
  const float* W2 = (const float*)d_in[5];
  const float* b2 = (const float*)d_in[6];
  const float* gnw = (const float*)d_in[7];
  const float* gnb = (const float*)d_in[8];
  const float* gna = (const float*)d_in[9];
  const float* lw = (const float*)d_in[10];
  const float* lb = (const float*)d_in[11];
  float* out = (float*)d_out;

  const int* srcI = ei;
  const int* dstI = ei + N_EDGES;

  char* p = (char*)d_ws;
  float* hbuf = (float*)(p + 0);                 // 10,240,000 B
  float* mbuf = (float*)(p + 10240000);          // 10,240,000 B
  float* gbuf = (float*)(p + 20480000);          // 10,240,000 B
  int* src_sorted = (int*)(p + 30720000);        // 1,280,000 B
  int* rowptr = (int*)(p + 32000000);            // 80,004 -> 80,128 B
  int* cursor = (int*)(p + 32080128);            // 80,000 -> 80,128 B
  int* deg = (int*)(p + 32160256);               // 80,000 -> 80,128 B
  float* cntf = (float*)(p + 32240512);          // 64 -> 128 B
  float* s1buf = (float*)(p + 32240640);         // 8192 B
  float* s2buf = (float*)(p + 32248832);         // 8192 B (contiguous with s1buf)
  float* pooled = (float*)(p + 32257024);        // 8192 B

  // CSR build (once per call; edges are layer-invariant)
  hipMemsetAsync(deg, 0, N_NODES * sizeof(int), stream);
  k_deg<<<N_EDGES / 256, 256, 0, stream>>>(dstI, deg);
  k_scan<<<1, 1024, 0, stream>>>(deg, rowptr, cursor, batch, cntf);
  k_fill<<<N_EDGES / 256, 256, 0, stream>>>(srcI, dstI, cursor, src_sorted);

  const float* hin = x;
  for (int i = 0; i < N_LAYERS; i++) {
    k_mlp<<<N_NODES / 16, 256, 0, stream>>>(hin, mbuf, W1 + (size_t)i * 128 * 64, b1 + (size_t)i * 64,
                                            W2 + (size_t)i * 64 * 128, b2 + (size_t)i * 128);
    k_scatter<<<N_NODES / 4, 256, 0, stream>>>(mbuf, gbuf, rowptr, src_sorted);
    hipMemsetAsync(s1buf, 0, 2 * N_GRAPHS * N_FEAT * sizeof(float), stream);  // zeroes s1+s2
    k_stats<<<N_NODES / STAT_CHUNK, 128, 0, stream>>>(gbuf, batch, s1buf, s2buf);
    k_apply<<<N_NODES * N_FEAT / 256, 256, 0, stream>>>(gbuf, hbuf, batch, s1buf, s2buf, cntf,
                                                        gnw + (size_t)i * 128, gnb + (size_t)i * 128,
                                                        gna + (size_t)i * 128, i > 0 ? 1 : 0);
    hin = hbuf;
  }

  hipMemsetAsync(pooled, 0, N_GRAPHS * N_FEAT * sizeof(float), stream);
  k_segsum<<<N_NODES / STAT_CHUNK, 128, 0, stream>>>(hbuf, batch, pooled);
  k_final<<<1, 256, 0, stream>>>(pooled, cntf, lw, lb, out);
}

// Round 3
// 429.642 us; speedup vs baseline: 1.9931x; 1.2008x over previous
//
#include <hip/hip_runtime.h>

#define N_NODES 20000
#define N_EDGES 320000
#define N_FEAT 128
#define MLP_HID 64
#define N_GRAPHS 16
#define N_LAYERS 5
#define EPS 1e-5f

__device__ inline float bf2f(unsigned short u) { return __uint_as_float(((unsigned)u) << 16); }
__device__ inline unsigned short f2bf(float f) {
  unsigned u = __float_as_uint(f);
  u += 0x7FFF + ((u >> 16) & 1);  // RNE
  return (unsigned short)(u >> 16);
}

// ---------------- CSR build ----------------

__global__ __launch_bounds__(256) void k_deg(const int* __restrict__ dst, int* __restrict__ deg) {
  int e = blockIdx.x * 256 + threadIdx.x;  // grid exact: 1250*256 = 320000
  atomicAdd(&deg[dst[e]], 1);
}

__global__ __launch_bounds__(1024) void k_scan(const int* __restrict__ deg, int* __restrict__ rowptr,
                                               int* __restrict__ cursor, const int* __restrict__ batch,
                                               float* __restrict__ cntf, float* __restrict__ pooled) {
  __shared__ int sdata[1024];
  __shared__ int spos[17];
  constexpr int CH = 20;  // 1024*20 = 20480 >= 20000
  int t = threadIdx.x;
  // zero the final pooling accumulator once per call (replaces a memset launch)
  for (int i = t; i < N_GRAPHS * N_FEAT; i += 1024) pooled[i] = 0.0f;
  int base = t * CH;
  int loc[CH];
  int partial = 0;
#pragma unroll
  for (int i = 0; i < CH; i++) {
    int idx = base + i;
    int v = (idx < N_NODES) ? deg[idx] : 0;
    loc[i] = v;
    partial += v;
  }
  sdata[t] = partial;
  __syncthreads();
  for (int off = 1; off < 1024; off <<= 1) {
    int v = (t >= off) ? sdata[t - off] : 0;
    __syncthreads();
    sdata[t] += v;
    __syncthreads();
  }
  int run = sdata[t] - partial;  // exclusive prefix
#pragma unroll
  for (int i = 0; i < CH; i++) {
    int idx = base + i;
    if (idx < N_NODES) {
      rowptr[idx] = run;
      cursor[idx] = run;
      run += loc[i];
    }
  }
  if (t == 1023) rowptr[N_NODES] = sdata[1023];
  // per-graph counts via binary search on sorted batch
  if (t < 17) {
    int lo = 0, hi = N_NODES;
    while (lo < hi) {
      int mid = (lo + hi) >> 1;
      if (batch[mid] < t) lo = mid + 1; else hi = mid;
    }
    spos[t] = lo;
  }
  __syncthreads();
  if (t < N_GRAPHS) cntf[t] = fmaxf((float)(spos[t + 1] - spos[t]), 1.0f);
}

__global__ __launch_bounds__(256) void k_fill(const int* __restrict__ src, const int* __restrict__ dst,
                                              int* __restrict__ cursor, int* __restrict__ src_sorted) {
  int e = blockIdx.x * 256 + threadIdx.x;  // grid exact
  int d = dst[e];
  int p = atomicAdd(&cursor[d], 1);
  src_sorted[p] = src[e];
}

// ---------------- per-node MLP: m = relu(h@W1+b1)@W2+b2, m stored bf16 ----------------

__global__ __launch_bounds__(256) void k_mlp(const float* __restrict__ hin, unsigned short* __restrict__ mout,
                                             const float* __restrict__ W1, const float* __restrict__ b1,
                                             const float* __restrict__ W2, const float* __restrict__ b2) {
  __shared__ float W1s[128 * 64];
  __shared__ float W2s[64 * 128];
  __shared__ float hs[16][128];
  __shared__ float hidS[16][64];
  __shared__ float b1s[64];
  __shared__ float b2s[128];
  int t = threadIdx.x;
  int r0 = blockIdx.x * 16;  // grid exact: 1250*16 = 20000
  {
    float4* w1v = (float4*)W1s;
    const float4* w1g = (const float4*)W1;
    float4* w2v = (float4*)W2s;
    const float4* w2g = (const float4*)W2;
    for (int i = t; i < 2048; i += 256) {
      w1v[i] = w1g[i];
      w2v[i] = w2g[i];
    }
    float4* hv = (float4*)hs;
    const float4* hg = (const float4*)(hin + (size_t)r0 * 128);
    for (int i = t; i < 512; i += 256) hv[i] = hg[i];
    if (t < 64) b1s[t] = b1[t];
    if (t < 128) b2s[t] = b2[t];
  }
  __syncthreads();
  // phase 1: hid[16][64]
  {
    int j = t & 63, rr = t >> 6;  // rows rr, rr+4, rr+8, rr+12
    float a0 = 0.f, a1 = 0.f, a2 = 0.f, a3 = 0.f;
#pragma unroll
    for (int c = 0; c < 128; c += 4) {
      float w0 = W1s[(c + 0) * 64 + j];
      float w1 = W1s[(c + 1) * 64 + j];
      float w2 = W1s[(c + 2) * 64 + j];
      float w3 = W1s[(c + 3) * 64 + j];
      float4 h0 = *(const float4*)&hs[rr][c];
      float4 h1 = *(const float4*)&hs[rr + 4][c];
      float4 h2 = *(const float4*)&hs[rr + 8][c];
      float4 h3 = *(const float4*)&hs[rr + 12][c];
      a0 += h0.x * w0 + h0.y * w1 + h0.z * w2 + h0.w * w3;
      a1 += h1.x * w0 + h1.y * w1 + h1.z * w2 + h1.w * w3;
      a2 += h2.x * w0 + h2.y * w1 + h2.z * w2 + h2.w * w3;
      a3 += h3.x * w0 + h3.y * w1 + h3.z * w2 + h3.w * w3;
    }
    float bb = b1s[j];
    hidS[rr][j] = fmaxf(a0 + bb, 0.0f);
    hidS[rr + 4][j] = fmaxf(a1 + bb, 0.0f);
    hidS[rr + 8][j] = fmaxf(a2 + bb, 0.0f);
    hidS[rr + 12][j] = fmaxf(a3 + bb, 0.0f);
  }
  __syncthreads();
  // phase 2: m[16][128] -> bf16
  {
    int j = t & 127, r2 = t >> 7;  // rows r2 + 2q
    float acc[8];
#pragma unroll
    for (int q = 0; q < 8; q++) acc[q] = 0.0f;
#pragma unroll
    for (int k = 0; k < 64; k += 4) {
      float w0 = W2s[(k + 0) * 128 + j];
      float w1 = W2s[(k + 1) * 128 + j];
      float w2 = W2s[(k + 2) * 128 + j];
      float w3 = W2s[(k + 3) * 128 + j];
#pragma unroll
      for (int q = 0; q < 8; q++) {
        float4 hh = *(const float4*)&hidS[r2 + 2 * q][k];
        acc[q] += hh.x * w0 + hh.y * w1 + hh.z * w2 + hh.w * w3;
      }
    }
    float bb = b2s[j];
#pragma unroll
    for (int q = 0; q < 8; q++) mout[(size_t)(r0 + r2 + 2 * q) * 128 + j] = f2bf(acc[q] + bb);
  }
}

// ---------------- scatter-add: g[n] = m[n] + sum m[src[e]], m is bf16 ----------------
// One wave per node; lane = (quarter, q16): q16 indexes a float4 (8 bf16 cols),
// quarter selects one of 4 edges per gather instruction -> 16 edges in flight.

__global__ __launch_bounds__(256) void k_scatter(const unsigned short* __restrict__ mbf, float* __restrict__ g,
                                                 const int* __restrict__ rowptr, const int* __restrict__ srcs,
                                                 float* __restrict__ s1, float* __restrict__ s2) {
  if (blockIdx.x == 0) {  // zero stats accumulators (k_stats dispatches later)
    for (int i = threadIdx.x; i < N_GRAPHS * N_FEAT; i += 256) { s1[i] = 0.0f; s2[i] = 0.0f; }
  }
  int node = (blockIdx.x * 256 + threadIdx.x) >> 6;  // grid exact: 5000*4 waves
  int lane = threadIdx.x & 63;
  int quarter = lane >> 4;
  int q16 = lane & 15;
  const float4* m4 = (const float4*)mbf;
  float acc[8];
  union BU { float4 f; unsigned short u[8]; };
  if (quarter == 0) {  // self loop
    BU U; U.f = m4[(size_t)node * 16 + q16];
#pragma unroll
    for (int j = 0; j < 8; j++) acc[j] = bf2f(U.u[j]);
  } else {
#pragma unroll
    for (int j = 0; j < 8; j++) acc[j] = 0.0f;
  }
  int e = rowptr[node], e1 = rowptr[node + 1];
  for (; e + 16 <= e1; e += 16) {
    int i0 = srcs[e + quarter];
    int i1 = srcs[e + 4 + quarter];
    int i2 = srcs[e + 8 + quarter];
    int i3 = srcs[e + 12 + quarter];
    BU U0, U1, U2, U3;
    U0.f = m4[(size_t)i0 * 16 + q16];
    U1.f = m4[(size_t)i1 * 16 + q16];
    U2.f = m4[(size_t)i2 * 16 + q16];
    U3.f = m4[(size_t)i3 * 16 + q16];
#pragma unroll
    for (int j = 0; j < 8; j++)
      acc[j] += (bf2f(U0.u[j]) + bf2f(U1.u[j])) + (bf2f(U2.u[j]) + bf2f(U3.u[j]));
  }
  for (; e + 4 <= e1; e += 4) {
    BU U0; U0.f = m4[(size_t)srcs[e + quarter] * 16 + q16];
#pragma unroll
    for (int j = 0; j < 8; j++) acc[j] += bf2f(U0.u[j]);
  }
  if (e + quarter < e1) {
    BU U0; U0.f = m4[(size_t)srcs[e + quarter] * 16 + q16];
#pragma unroll
    for (int j = 0; j < 8; j++) acc[j] += bf2f(U0.u[j]);
  }
#pragma unroll
  for (int j = 0; j < 8; j++) {
    acc[j] += __shfl_xor(acc[j], 16);
    acc[j] += __shfl_xor(acc[j], 32);
  }
  if (quarter == 0) {
    float4* g4 = (float4*)(g + (size_t)node * 128 + q16 * 8);
    g4[0] = make_float4(acc[0], acc[1], acc[2], acc[3]);
    g4[1] = make_float4(acc[4], acc[5], acc[6], acc[7]);
  }
}

// ---------------- one-pass segment stats: s1 = sum(g), s2 = sum(g^2) ----------------

#define STAT_CHUNK 8  // 2500 blocks * 8 = 20000 exact

__global__ __launch_bounds__(128) void k_stats(const float* __restrict__ in, const int* __restrict__ batch,
                                               float* __restrict__ s1, float* __restrict__ s2) {
  int n0 = blockIdx.x * STAT_CHUNK;
  int c = threadIdx.x;
  int curg = batch[n0];
  float a1 = 0.0f, a2 = 0.0f;
#pragma unroll
  for (int k = 0; k < STAT_CHUNK; k++) {
    int n = n0 + k;
    int gg = batch[n];
    if (gg != curg) {  // block-uniform branch (batch sorted)
      atomicAdd(&s1[curg * 128 + c], a1);
      atomicAdd(&s2[curg * 128 + c], a2);
      a1 = 0.0f; a2 = 0.0f;
      curg = gg;
    }
    float v = in[(size_t)n * 128 + c];
    a1 += v;
    a2 += v * v;
  }
  atomicAdd(&s1[curg * 128 + c], a1);
  atomicAdd(&s2[curg * 128 + c], a2);
}

__global__ __launch_bounds__(128) void k_segsum(const float* __restrict__ in, const int* __restrict__ batch,
                                                float* __restrict__ outbuf) {
  int n0 = blockIdx.x * STAT_CHUNK;
  int c = threadIdx.x;
  int curg = batch[n0];
  float acc = 0.0f;
#pragma unroll
  for (int k = 0; k < STAT_CHUNK; k++) {
    int n = n0 + k;
    int gg = batch[n];
    if (gg != curg) {
      atomicAdd(&outbuf[curg * 128 + c], acc);
      acc = 0.0f;
      curg = gg;
    }
    acc += in[(size_t)n * 128 + c];
  }
  atomicAdd(&outbuf[curg * 128 + c], acc);
}

// ---------------- normalize + affine + relu + residual (float4) ----------------
// var = E[(h - a*mean)^2] = E[h^2] - mean^2*(2a - a^2)

__global__ __launch_bounds__(256) void k_apply(const float* __restrict__ gin, float* __restrict__ h,
                                               const int* __restrict__ batch,
                                               const float* __restrict__ s1, const float* __restrict__ s2,
                                               const float* __restrict__ cntf,
                                               const float* __restrict__ w, const float* __restrict__ b,
                                               const float* __restrict__ a, int residual) {
  int idx = blockIdx.x * 256 + threadIdx.x;  // float4 index; grid exact: 2500*256 = 640,000
  int n = idx >> 5, c4 = idx & 31;
  int gg = batch[n];
  float invc = 1.0f / cntf[gg];
  float4 sm = ((const float4*)s1)[gg * 32 + c4];
  float4 se = ((const float4*)s2)[gg * 32 + c4];
  float4 av = ((const float4*)a)[c4];
  float4 wv = ((const float4*)w)[c4];
  float4 bv = ((const float4*)b)[c4];
  float4 gv = ((const float4*)gin)[idx];
  float4 hv = make_float4(0.f, 0.f, 0.f, 0.f);
  if (residual) hv = ((const float4*)h)[idx];
  float4 o;
#define APPLY1(X)                                                          \
  {                                                                        \
    float mean = sm.X * invc;                                              \
    float ex2 = se.X * invc;                                               \
    float ac = av.X;                                                       \
    float var = fmaxf(ex2 - mean * mean * (2.0f * ac - ac * ac), 0.0f);    \
    float d = gv.X - ac * mean;                                            \
    float y = wv.X * (d * rsqrtf(var + EPS)) + bv.X;                       \
    y = fmaxf(y, 0.0f);                                                    \
    o.X = residual ? (y + hv.X) : y;                                       \
  }
  APPLY1(x) APPLY1(y) APPLY1(z) APPLY1(w)
#undef APPLY1
  ((float4*)h)[idx] = o;
}

// ---------------- final pooled @ lin_w + lin_b ----------------

__global__ __launch_bounds__(256) void k_final(const float* __restrict__ pooled, const float* __restrict__ cntf,
                                               const float* __restrict__ lw, const float* __restrict__ lb,
                                               float* __restrict__ out) {
  int lane = threadIdx.x & 63, wave = threadIdx.x >> 6;
  for (int gi = 0; gi < 4; gi++) {
    int gidx = wave * 4 + gi;
    float s = pooled[gidx * 128 + lane] * lw[lane] + pooled[gidx * 128 + 64 + lane] * lw[64 + lane];
    for (int o = 32; o >= 1; o >>= 1) s += __shfl_down(s, o);
    if (lane == 0) out[gidx] = s / cntf[gidx] + lb[0];
  }
}

// ---------------- host ----------------

extern "C" void kernel_launch(void* const* d_in, const int* in_sizes, int n_in,
                              void* d_out, int out_size, void* d_ws, size_t ws_size,
                              hipStream_t stream) {
  const float* x = (const float*)d_in[0];
  const int* ei = (const int*)d_in[1];
  const int* batch = (const int*)d_in[2];
  const float* W1 = (const float*)d_in[3];
  const float* b1 = (const float*)d_in[4];
  const float* W2 = (const float*)d_in[5];
  const float* b2 = (const float*)d_in[6];
  const float* gnw = (const float*)d_in[7];
  const float* gnb = (const float*)d_in[8];
  const float* gna = (const float*)d_in[9];
  const float* lw = (const float*)d_in[10];
  const float* lb = (const float*)d_in[11];
  float* out = (float*)d_out;

  const int* srcI = ei;
  const int* dstI = ei + N_EDGES;

  char* p = (char*)d_ws;
  float* hbuf = (float*)(p + 0);                 // 10,240,000 B
  unsigned short* mbuf = (unsigned short*)(p + 10240000);  // 5,120,000 B (bf16)
  float* gbuf = (float*)(p + 20480000);          // 10,240,000 B
  int* src_sorted = (int*)(p + 30720000);        // 1,280,000 B
  int* rowptr = (int*)(p + 32000000);
  int* cursor = (int*)(p + 32080128);
  int* deg = (int*)(p + 32160256);
  float* cntf = (float*)(p + 32240512);
  float* s1buf = (float*)(p + 32240640);         // 8192 B
  float* s2buf = (float*)(p + 32248832);         // 8192 B
  float* pooled = (float*)(p + 32257024);        // 8192 B

  // CSR build (once per call; edges are layer-invariant)
  hipMemsetAsync(deg, 0, N_NODES * sizeof(int), stream);
  k_deg<<<N_EDGES / 256, 256, 0, stream>>>(dstI, deg);
  k_scan<<<1, 1024, 0, stream>>>(deg, rowptr, cursor, batch, cntf, pooled);
  k_fill<<<N_EDGES / 256, 256, 0, stream>>>(srcI, dstI, cursor, src_sorted);

  const float* hin = x;
  for (int i = 0; i < N_LAYERS; i++) {
    k_mlp<<<N_NODES / 16, 256, 0, stream>>>(hin, mbuf, W1 + (size_t)i * 128 * 64, b1 + (size_t)i * 64,
                                            W2 + (size_t)i * 64 * 128, b2 + (size_t)i * 128);
    k_scatter<<<N_NODES / 4, 256, 0, stream>>>(mbuf, gbuf, rowptr, src_sorted, s1buf, s2buf);
    k_stats<<<N_NODES / STAT_CHUNK, 128, 0, stream>>>(gbuf, batch, s1buf, s2buf);
    k_apply<<<N_NODES * N_FEAT / 4 / 256, 256, 0, stream>>>(gbuf, hbuf, batch, s1buf, s2buf, cntf,
                                                            gnw + (size_t)i * 128, gnb + (size_t)i * 128,
                                                            gna + (size_t)i * 128, i > 0 ? 1 : 0);
    hin = hbuf;
  }

  k_segsum<<<N_NODES / STAT_CHUNK, 128, 0, stream>>>(hbuf, batch, pooled);
  k_final<<<1, 256, 0, stream>>>(pooled, cntf, lw, lb, out);
}

// Round 4
// 335.554 us; speedup vs baseline: 2.5519x; 1.2804x over previous
//
#include <hip/hip_runtime.h>

#define N_NODES 20000
#define N_EDGES 320000
#define N_FEAT 128
#define MLP_HID 64
#define N_GRAPHS 16
#define N_LAYERS 5
#define EPS 1e-5f

typedef __attribute__((ext_vector_type(8))) short short8;   // 8 bf16 = 4 VGPRs (MFMA A/B frag)
typedef __attribute__((ext_vector_type(4))) float f32x4;    // MFMA C/D frag

__device__ inline float bf2f(unsigned short u) { return __uint_as_float(((unsigned)u) << 16); }
__device__ inline unsigned short f2bf(float f) {
  unsigned u = __float_as_uint(f);
  u += 0x7FFF + ((u >> 16) & 1);  // RNE
  return (unsigned short)(u >> 16);
}

// ---------------- CSR build ----------------

__global__ __launch_bounds__(256) void k_deg(const int* __restrict__ dst, int* __restrict__ deg) {
  int e = blockIdx.x * 256 + threadIdx.x;  // grid exact: 1250*256 = 320000
  atomicAdd(&deg[dst[e]], 1);
}

__global__ __launch_bounds__(1024) void k_scan(const int* __restrict__ deg, int* __restrict__ rowptr,
                                               int* __restrict__ cursor, const int* __restrict__ batch,
                                               float* __restrict__ cntf, float* __restrict__ pooled) {
  __shared__ int sdata[1024];
  __shared__ int spos[17];
  constexpr int CH = 20;  // 1024*20 = 20480 >= 20000
  int t = threadIdx.x;
  for (int i = t; i < N_GRAPHS * N_FEAT; i += 1024) pooled[i] = 0.0f;
  int base = t * CH;
  int loc[CH];
  int partial = 0;
#pragma unroll
  for (int i = 0; i < CH; i++) {
    int idx = base + i;
    int v = (idx < N_NODES) ? deg[idx] : 0;
    loc[i] = v;
    partial += v;
  }
  sdata[t] = partial;
  __syncthreads();
  for (int off = 1; off < 1024; off <<= 1) {
    int v = (t >= off) ? sdata[t - off] : 0;
    __syncthreads();
    sdata[t] += v;
    __syncthreads();
  }
  int run = sdata[t] - partial;  // exclusive prefix
#pragma unroll
  for (int i = 0; i < CH; i++) {
    int idx = base + i;
    if (idx < N_NODES) {
      rowptr[idx] = run;
      cursor[idx] = run;
      run += loc[i];
    }
  }
  if (t == 1023) rowptr[N_NODES] = sdata[1023];
  if (t < 17) {  // per-graph counts via binary search on sorted batch
    int lo = 0, hi = N_NODES;
    while (lo < hi) {
      int mid = (lo + hi) >> 1;
      if (batch[mid] < t) lo = mid + 1; else hi = mid;
    }
    spos[t] = lo;
  }
  __syncthreads();
  if (t < N_GRAPHS) cntf[t] = fmaxf((float)(spos[t + 1] - spos[t]), 1.0f);
}

__global__ __launch_bounds__(256) void k_fill(const int* __restrict__ src, const int* __restrict__ dst,
                                              int* __restrict__ cursor, int* __restrict__ src_sorted) {
  int e = blockIdx.x * 256 + threadIdx.x;  // grid exact
  int d = dst[e];
  int p = atomicAdd(&cursor[d], 1);
  src_sorted[p] = src[e];
}

// ---------------- weight prep: bf16 + transpose (once per call) ----------------
// W1t[l][n=64][k=128] = W1[l][k][n];  W2t[l][n=128][k=64] = W2[l][k][n]

__global__ __launch_bounds__(256) void k_prep(const float* __restrict__ W1, const float* __restrict__ W2,
                                              unsigned short* __restrict__ w1t, unsigned short* __restrict__ w2t) {
  int idx = blockIdx.x * 256 + threadIdx.x;  // grid exact: 320*256 = 81920
  if (idx < 40960) {
    int l = idx >> 13, rem = idx & 8191;
    int n = rem >> 7, k = rem & 127;
    w1t[idx] = f2bf(W1[l * 8192 + k * 64 + n]);
  } else {
    int j = idx - 40960;
    int l = j >> 13, rem = j & 8191;
    int n = rem >> 6, k = rem & 63;
    w2t[j] = f2bf(W2[l * 8192 + k * 128 + n]);
  }
}

// ---------------- per-node MLP via MFMA: m = relu(h@W1+b1)@W2+b2, m stored bf16 ----------------
// 64 nodes/block, 4 waves; wave w computes rows [w*16, w*16+16).
// mfma_f32_16x16x32_bf16: A[m=lane&15][k=quad*8+j], B[k=quad*8+j][n=lane&15],
// C/D: col=lane&15, row=quad*4+reg.

#define PADK 136  // 128+8 shorts: +16B row pad breaks LDS bank conflicts
#define PADH 72   // 64+8

__global__ __launch_bounds__(256) void k_mlp(const float* __restrict__ hin, unsigned short* __restrict__ mout,
                                             const unsigned short* __restrict__ w1t,
                                             const unsigned short* __restrict__ w2t,
                                             const float* __restrict__ b1, const float* __restrict__ b2) {
  __shared__ __align__(16) short hS[64 * PADK];   // h bf16; reused as m-out after phase 1
  __shared__ __align__(16) short w1S[64 * PADK];  // W1^T [n][k]
  __shared__ __align__(16) short hidS[64 * PADH]; // hidden [m][k]
  __shared__ __align__(16) short w2S[128 * PADH]; // W2^T [n][k]
  __shared__ float b1S[64];
  __shared__ float b2S[128];
  int t = threadIdx.x;
  int r0 = blockIdx.x * 64;  // grid 313: last block covers 32 valid rows
  // stage h (fp32 global -> bf16 LDS)
#pragma unroll
  for (int i = 0; i < 8; i++) {
    int idx = t + i * 256;  // float4 id, 2048 total
    int row = idx >> 5, c4 = idx & 31;
    float4 v = (r0 + row < N_NODES) ? ((const float4*)hin)[(size_t)(r0 + row) * 32 + c4]
                                    : make_float4(0.f, 0.f, 0.f, 0.f);
    ushort4 s;
    s.x = f2bf(v.x); s.y = f2bf(v.y); s.z = f2bf(v.z); s.w = f2bf(v.w);
    *(ushort4*)&hS[row * PADK + c4 * 4] = s;
  }
  // stage W1t (64x128 shorts = 1024 16B chunks) and W2t (128x64)
#pragma unroll
  for (int i = 0; i < 4; i++) {
    int idx = t + i * 256;
    *(int4*)&w1S[(idx >> 4) * PADK + (idx & 15) * 8] = ((const int4*)w1t)[idx];
    *(int4*)&w2S[(idx >> 3) * PADH + (idx & 7) * 8] = ((const int4*)w2t)[idx];
  }
  if (t < 64) b1S[t] = b1[t];
  else if (t < 192) b2S[t - 64] = b2[t - 64];
  __syncthreads();

  int w = t >> 6, lane = t & 63, lm = lane & 15, quad = lane >> 4;
  int mrow = w * 16 + lm;          // A-operand row for this lane
  int orow = w * 16 + quad * 4;    // C/D base row for this lane

  // phase 1: hid[64][64] = relu(h @ W1 + b1)
  f32x4 zero = {0.f, 0.f, 0.f, 0.f};
  f32x4 acc[4] = {zero, zero, zero, zero};
#pragma unroll
  for (int k0 = 0; k0 < 128; k0 += 32) {
    short8 a = *(const short8*)&hS[mrow * PADK + k0 + quad * 8];
#pragma unroll
    for (int nt = 0; nt < 4; nt++) {
      short8 b = *(const short8*)&w1S[(nt * 16 + lm) * PADK + k0 + quad * 8];
      acc[nt] = __builtin_amdgcn_mfma_f32_16x16x32_bf16(a, b, acc[nt], 0, 0, 0);
    }
  }
#pragma unroll
  for (int nt = 0; nt < 4; nt++) {
    int col = nt * 16 + lm;
    float bb = b1S[col];
#pragma unroll
    for (int r = 0; r < 4; r++)
      hidS[(orow + r) * PADH + col] = (short)f2bf(fmaxf(acc[nt][r] + bb, 0.0f));
  }
  __syncthreads();  // hidS ready; hS no longer read -> reusable as m-out

  // phase 2: m[64][128] = hid @ W2 + b2
  f32x4 acc2[8] = {zero, zero, zero, zero, zero, zero, zero, zero};
#pragma unroll
  for (int k0 = 0; k0 < 64; k0 += 32) {
    short8 a = *(const short8*)&hidS[mrow * PADH + k0 + quad * 8];
#pragma unroll
    for (int nt = 0; nt < 8; nt++) {
      short8 b = *(const short8*)&w2S[(nt * 16 + lm) * PADH + k0 + quad * 8];
      acc2[nt] = __builtin_amdgcn_mfma_f32_16x16x32_bf16(a, b, acc2[nt], 0, 0, 0);
    }
  }
#pragma unroll
  for (int nt = 0; nt < 8; nt++) {
    int col = nt * 16 + lm;
    float bb = b2S[col];
#pragma unroll
    for (int r = 0; r < 4; r++)
      hS[(orow + r) * PADK + col] = (short)f2bf(acc2[nt][r] + bb);
  }
  __syncthreads();
  // coalesced bf16 store of m
#pragma unroll
  for (int i = 0; i < 4; i++) {
    int idx = t + i * 256;
    int row = idx >> 4, cc = idx & 15;
    if (r0 + row < N_NODES)
      ((int4*)mout)[(size_t)(r0 + row) * 16 + cc] = *(const int4*)&hS[row * PADK + cc * 8];
  }
}

// ---------------- scatter-add: g[n] = m[n] + sum m[src[e]], m is bf16 ----------------

__global__ __launch_bounds__(256) void k_scatter(const unsigned short* __restrict__ mbf, float* __restrict__ g,
                                                 const int* __restrict__ rowptr, const int* __restrict__ srcs,
                                                 float* __restrict__ s1, float* __restrict__ s2) {
  if (blockIdx.x == 0) {  // zero stats accumulators (k_stats dispatches later)
    for (int i = threadIdx.x; i < N_GRAPHS * N_FEAT; i += 256) { s1[i] = 0.0f; s2[i] = 0.0f; }
  }
  int node = (blockIdx.x * 256 + threadIdx.x) >> 6;  // grid exact: 5000*4 waves
  int lane = threadIdx.x & 63;
  int quarter = lane >> 4;
  int q16 = lane & 15;
  const float4* m4 = (const float4*)mbf;
  float acc[8];
  union BU { float4 f; unsigned short u[8]; };
  if (quarter == 0) {  // self loop
    BU U; U.f = m4[(size_t)node * 16 + q16];
#pragma unroll
    for (int j = 0; j < 8; j++) acc[j] = bf2f(U.u[j]);
  } else {
#pragma unroll
    for (int j = 0; j < 8; j++) acc[j] = 0.0f;
  }
  int e = rowptr[node], e1 = rowptr[node + 1];
  for (; e + 16 <= e1; e += 16) {
    int i0 = srcs[e + quarter];
    int i1 = srcs[e + 4 + quarter];
    int i2 = srcs[e + 8 + quarter];
    int i3 = srcs[e + 12 + quarter];
    BU U0, U1, U2, U3;
    U0.f = m4[(size_t)i0 * 16 + q16];
    U1.f = m4[(size_t)i1 * 16 + q16];
    U2.f = m4[(size_t)i2 * 16 + q16];
    U3.f = m4[(size_t)i3 * 16 + q16];
#pragma unroll
    for (int j = 0; j < 8; j++)
      acc[j] += (bf2f(U0.u[j]) + bf2f(U1.u[j])) + (bf2f(U2.u[j]) + bf2f(U3.u[j]));
  }
  for (; e + 4 <= e1; e += 4) {
    BU U0; U0.f = m4[(size_t)srcs[e + quarter] * 16 + q16];
#pragma unroll
    for (int j = 0; j < 8; j++) acc[j] += bf2f(U0.u[j]);
  }
  if (e + quarter < e1) {
    BU U0; U0.f = m4[(size_t)srcs[e + quarter] * 16 + q16];
#pragma unroll
    for (int j = 0; j < 8; j++) acc[j] += bf2f(U0.u[j]);
  }
#pragma unroll
  for (int j = 0; j < 8; j++) {
    acc[j] += __shfl_xor(acc[j], 16);
    acc[j] += __shfl_xor(acc[j], 32);
  }
  if (quarter == 0) {
    float4* g4 = (float4*)(g + (size_t)node * 128 + q16 * 8);
    g4[0] = make_float4(acc[0], acc[1], acc[2], acc[3]);
    g4[1] = make_float4(acc[4], acc[5], acc[6], acc[7]);
  }
}

// ---------------- one-pass segment stats: s1 = sum(g), s2 = sum(g^2) ----------------

#define STAT_CHUNK 8  // 2500 blocks * 8 = 20000 exact

__global__ __launch_bounds__(128) void k_stats(const float* __restrict__ in, const int* __restrict__ batch,
                                               float* __restrict__ s1, float* __restrict__ s2) {
  int n0 = blockIdx.x * STAT_CHUNK;
  int c = threadIdx.x;
  int curg = batch[n0];
  float a1 = 0.0f, a2 = 0.0f;
#pragma unroll
  for (int k = 0; k < STAT_CHUNK; k++) {
    int n = n0 + k;
    int gg = batch[n];
    if (gg != curg) {  // block-uniform branch (batch sorted)
      atomicAdd(&s1[curg * 128 + c], a1);
      atomicAdd(&s2[curg * 128 + c], a2);
      a1 = 0.0f; a2 = 0.0f;
      curg = gg;
    }
    float v = in[(size_t)n * 128 + c];
    a1 += v;
    a2 += v * v;
  }
  atomicAdd(&s1[curg * 128 + c], a1);
  atomicAdd(&s2[curg * 128 + c], a2);
}

__global__ __launch_bounds__(128) void k_segsum(const float* __restrict__ in, const int* __restrict__ batch,
                                                float* __restrict__ outbuf) {
  int n0 = blockIdx.x * STAT_CHUNK;
  int c = threadIdx.x;
  int curg = batch[n0];
  float acc = 0.0f;
#pragma unroll
  for (int k = 0; k < STAT_CHUNK; k++) {
    int n = n0 + k;
    int gg = batch[n];
    if (gg != curg) {
      atomicAdd(&outbuf[curg * 128 + c], acc);
      acc = 0.0f;
      curg = gg;
    }
    acc += in[(size_t)n * 128 + c];
  }
  atomicAdd(&outbuf[curg * 128 + c], acc);
}

// ---------------- normalize + affine + relu + residual (float4) ----------------
// var = E[(h - a*mean)^2] = E[h^2] - mean^2*(2a - a^2)

__global__ __launch_bounds__(256) void k_apply(const float* __restrict__ gin, float* __restrict__ h,
                                               const int* __restrict__ batch,
                                               const float* __restrict__ s1, const float* __restrict__ s2,
                                               const float* __restrict__ cntf,
                                               const float* __restrict__ w, const float* __restrict__ b,
                                               const float* __restrict__ a, int residual) {
  int idx = blockIdx.x * 256 + threadIdx.x;  // float4 index; grid exact: 2500*256 = 640,000
  int n = idx >> 5, c4 = idx & 31;
  int gg = batch[n];
  float invc = 1.0f / cntf[gg];
  float4 sm = ((const float4*)s1)[gg * 32 + c4];
  float4 se = ((const float4*)s2)[gg * 32 + c4];
  float4 av = ((const float4*)a)[c4];
  float4 wv = ((const float4*)w)[c4];
  float4 bv = ((const float4*)b)[c4];
  float4 gv = ((const float4*)gin)[idx];
  float4 hv = make_float4(0.f, 0.f, 0.f, 0.f);
  if (residual) hv = ((const float4*)h)[idx];
  float4 o;
#define APPLY1(X)                                                          \
  {                                                                        \
    float mean = sm.X * invc;                                              \
    float ex2 = se.X * invc;                                               \
    float ac = av.X;                                                       \
    float var = fmaxf(ex2 - mean * mean * (2.0f * ac - ac * ac), 0.0f);    \
    float d = gv.X - ac * mean;                                            \
    float y = wv.X * (d * rsqrtf(var + EPS)) + bv.X;                       \
    y = fmaxf(y, 0.0f);                                                    \
    o.X = residual ? (y + hv.X) : y;                                       \
  }
  APPLY1(x) APPLY1(y) APPLY1(z) APPLY1(w)
#undef APPLY1
  ((float4*)h)[idx] = o;
}

// ---------------- final pooled @ lin_w + lin_b ----------------

__global__ __launch_bounds__(256) void k_final(const float* __restrict__ pooled, const float* __restrict__ cntf,
                                               const float* __restrict__ lw, const float* __restrict__ lb,
                                               float* __restrict__ out) {
  int lane = threadIdx.x & 63, wave = threadIdx.x >> 6;
  for (int gi = 0; gi < 4; gi++) {
    int gidx = wave * 4 + gi;
    float s = pooled[gidx * 128 + lane] * lw[lane] + pooled[gidx * 128 + 64 + lane] * lw[64 + lane];
    for (int o = 32; o >= 1; o >>= 1) s += __shfl_down(s, o);
    if (lane == 0) out[gidx] = s / cntf[gidx] + lb[0];
  }
}

// ---------------- host ----------------

extern "C" void kernel_launch(void* const* d_in, const int* in_sizes, int n_in,
                              void* d_out, int out_size, void* d_ws, size_t ws_size,
                              hipStream_t stream) {
  const float* x = (const float*)d_in[0];
  const int* ei = (const int*)d_in[1];
  const int* batch = (const int*)d_in[2];
  const float* W1 = (const float*)d_in[3];
  const float* b1 = (const float*)d_in[4];
  const float* W2 = (const float*)d_in[5];
  const float* b2 = (const float*)d_in[6];
  const float* gnw = (const float*)d_in[7];
  const float* gnb = (const float*)d_in[8];
  const float* gna = (const float*)d_in[9];
  const float* lw = (const float*)d_in[10];
  const float* lb = (const float*)d_in[11];
  float* out = (float*)d_out;

  const int* srcI = ei;
  const int* dstI = ei + N_EDGES;

  char* p = (char*)d_ws;
  float* hbuf = (float*)(p + 0);                           // 10,240,000 B
  unsigned short* mbuf = (unsigned short*)(p + 10240000);  // 5,120,000 B (bf16)
  float* gbuf = (float*)(p + 20480000);                    // 10,240,000 B
  int* src_sorted = (int*)(p + 30720000);                  // 1,280,000 B
  int* rowptr = (int*)(p + 32000000);
  int* cursor = (int*)(p + 32080128);
  int* deg = (int*)(p + 32160256);
  float* cntf = (float*)(p + 32240512);
  float* s1buf = (float*)(p + 32240640);                   // 8192 B
  float* s2buf = (float*)(p + 32248832);                   // 8192 B
  float* pooled = (float*)(p + 32257024);                  // 8192 B
  unsigned short* w1t = (unsigned short*)(p + 32265216);   // 81,920 B (5 layers bf16 W1^T)
  unsigned short* w2t = (unsigned short*)(p + 32347136);   // 81,920 B (5 layers bf16 W2^T)

  // CSR build + weight prep (once per call; edges & weights are layer-invariant)
  hipMemsetAsync(deg, 0, N_NODES * sizeof(int), stream);
  k_deg<<<N_EDGES / 256, 256, 0, stream>>>(dstI, deg);
  k_scan<<<1, 1024, 0, stream>>>(deg, rowptr, cursor, batch, cntf, pooled);
  k_fill<<<N_EDGES / 256, 256, 0, stream>>>(srcI, dstI, cursor, src_sorted);
  k_prep<<<320, 256, 0, stream>>>(W1, W2, w1t, w2t);

  const float* hin = x;
  for (int i = 0; i < N_LAYERS; i++) {
    k_mlp<<<(N_NODES + 63) / 64, 256, 0, stream>>>(hin, mbuf, w1t + (size_t)i * 8192, w2t + (size_t)i * 8192,
                                                   b1 + (size_t)i * 64, b2 + (size_t)i * 128);
    k_scatter<<<N_NODES / 4, 256, 0, stream>>>(mbuf, gbuf, rowptr, src_sorted, s1buf, s2buf);
    k_stats<<<N_NODES / STAT_CHUNK, 128, 0, stream>>>(gbuf, batch, s1buf, s2buf);
    k_apply<<<N_NODES * N_FEAT / 4 / 256, 256, 0, stream>>>(gbuf, hbuf, batch, s1buf, s2buf, cntf,
                                                            gnw + (size_t)i * 128, gnb + (size_t)i * 128,
                                                            gna + (size_t)i * 128, i > 0 ? 1 : 0);
    hin = hbuf;
  }

  k_segsum<<<N_NODES / STAT_CHUNK, 128, 0, stream>>>(hbuf, batch, pooled);
  k_final<<<1, 256, 0, stream>>>(pooled, cntf, lw, lb, out);
}